// Round 9
// baseline (376.235 us; speedup 1.0000x reference)
//
#include <hip/hip_runtime.h>
#include <cstdint>
#include <cstddef>

// ============================================================================
// MechanismGrabber on MI355X (gfx950)
//
// selected[n,d] = sum_{m,e} a[n,m]*x[n,e]*Wm[m,d,e] + sum_m a[n,m]*(bm+cm)[m,d]
// == single GEMM: (N=32768) x (K=16448) x (D=256) with A generated on the fly.
//
// R8: BARRIER-FREE main loop. B-fragments stream L2->registers directly
//     (global_load_dwordx4 on the fragment-contiguous Wcat layout), named
//     bf0/bf1 double-buffer two chunks ahead (WAR on regs sequences loads
//     after consumers; compiler-managed vmcnt). LDS holds only the read-only
//     a-tile (32 KB, one prologue barrier). Waves free-run -> MFMA/VALU/L2
//     overlap across the CU with no convergence dead-time.
// ============================================================================

typedef _Float16 f16;
typedef f16 f16x8 __attribute__((ext_vector_type(8)));
typedef float f32x4 __attribute__((ext_vector_type(4)));
typedef float f32x16 __attribute__((ext_vector_type(16)));

#define DEV __device__ __forceinline__

DEV uint32_t swz128(uint32_t b) { return b ^ (((b >> 7) & 7u) << 4); }

DEV void gload_lds16(const void* g, void* l) {
  __builtin_amdgcn_global_load_lds(
      (const __attribute__((address_space(1))) unsigned int*)g,
      (__attribute__((address_space(3))) unsigned int*)l, 16, 0, 0);
}

DEV f16x8 cvt8(float4 u0, float4 u1) {
  f16x8 v = {(f16)u0.x, (f16)u0.y, (f16)u0.z, (f16)u0.w,
             (f16)u1.x, (f16)u1.y, (f16)u1.z, (f16)u1.w};
  return v;
}

// ---------------------------------------------------------------------------
// prep for gemm_tpl (16x16x32 path, selector/integrate): unchanged.
// ---------------------------------------------------------------------------
__global__ void prep_b_kernel(const float* __restrict__ S, f16* __restrict__ dst,
                              int K, int BN, int total) {
  int t = blockIdx.x * 256 + threadIdx.x;
  if (t >= total) return;
  int gpc = BN * 8;
  int g = t % gpc;
  int c = (t / gpc) % (K / 64);
  int cb = t / (gpc * (K / 64));
  int ks = g / (BN * 4);
  int rem = g % (BN * 4);
  int col = rem >> 2;
  int kg = rem & 3;
  int J = cb * BN + col;
  int k = c * 64 + ks * 32 + kg * 8;
  const float* s = S + (size_t)J * K + k;
  float4 u0 = *(const float4*)s;
  float4 u1 = *(const float4*)(s + 4);
  f16* chunk = dst + (size_t)(cb * (K / 64) + c) * (BN * 64);
  *(f16x8*)((char*)chunk + swz128((uint32_t)g * 16)) = cvt8(u0, u1);
}

// ---------------------------------------------------------------------------
// Wcat: [cb 0..3][c 0..259] sub-chunks of 64k x 64col = 8 KB (linear,
// per-lane fragment-contiguous). group g = kstep*128 + khalf*64 + col64,
// byte g*16, holds B[k][col] for k = kstep*16 + khalf*8 + (0..7),
// col = cb*64 + col64.
// c<256: er=c>>6, m=c&63; value[k][col] = Wm[m][col][er*64+k].
// c==256: value[k][col] = bm[k][col]+cm[k][col].  c>=257: dummy.
// ---------------------------------------------------------------------------
__global__ void prep_wcat_kernel(const float* __restrict__ Wm,
                                 const float* __restrict__ bm,
                                 const float* __restrict__ cm,
                                 f16* __restrict__ dst) {
  int t = blockIdx.x * 256 + threadIdx.x;
  if (t >= 4 * 257 * 512) return;
  int g = t & 511;
  int gc = t >> 9;
  int c = gc % 257;
  int cb = gc / 257;
  int kstep = g >> 7;          // 0..3
  int khalf = (g >> 6) & 1;    // 0..1
  int col = cb * 64 + (g & 63);
  int k0 = kstep * 16 + khalf * 8;
  f16x8 v;
  if (c < 256) {
    int m = c & 63;
    int e0 = (c >> 6) * 64 + k0;
    const float* s = Wm + ((size_t)m * 256 + col) * 256 + e0;
    float4 u0 = *(const float4*)s;
    float4 u1 = *(const float4*)(s + 4);
    v = cvt8(u0, u1);
  } else {
#pragma unroll
    for (int j = 0; j < 8; ++j) {
      int k = k0 + j;
      v[j] = (f16)(bm[k * 256 + col] + cm[k * 256 + col]);
    }
  }
  *(f16x8*)(dst + ((size_t)(cb * 260 + c)) * 4096 + (size_t)g * 8) = v;
}

// ---------------------------------------------------------------------------
// Generic MFMA GEMM (selector + integrate phases). Unchanged.
// ---------------------------------------------------------------------------
template <int BN, int NCHUNK, int A0C, int EPI>
__global__ __launch_bounds__(BN == 256 ? 512 : 256, 2)
void gemm_tpl(const float* __restrict__ A0, int lda0,
              const f16* __restrict__ A1, int lda1,
              const f16* __restrict__ Bt,
              const float* __restrict__ bias,
              float* __restrict__ outF, f16* __restrict__ outH, int ldo) {
  constexpr int WAVES = (BN == 256) ? 8 : 4;
  constexpr int THREADS = WAVES * 64;
  constexpr int WC = (BN == 256) ? 4 : 1;
  constexpr int WR = WAVES / WC;
  constexpr int RT = 128 / (WR * 16);
  constexpr int CT = (BN / WC) / 16;

  __shared__ alignas(16) f16 sA[2][128 * 64];
  __shared__ alignas(16) f16 sB[2][BN * 64];

  const int tid = threadIdx.x;
  const int lane = tid & 63;
  const int wid = tid >> 6;
  const int wr = wid / WC, wc = wid % WC;
  const int rb = blockIdx.x, cb = blockIdx.y;

  auto stageB = [&](int c, int buf) {
    const char* src = (const char*)(Bt + (size_t)(cb * NCHUNK + c) * (BN * 64));
#pragma unroll
    for (int it = 0; it < (BN * 64 * 2) / (THREADS * 16); ++it) {
      int off = (it * THREADS + tid) * 16;
      gload_lds16(src + off, (char*)&sB[buf][0] + off);
    }
  };
  auto stageA = [&](int c, int buf) {
#pragma unroll
    for (int it = 0; it < 1024 / THREADS; ++it) {
      int gg = it * THREADS + tid;
      int row = gg >> 3, eg = gg & 7;
      size_t rowG = (size_t)rb * 128 + row;
      f16x8 v;
      if (A0C > 0 && c < A0C) {
        const float* s = A0 + rowG * lda0 + c * 64 + eg * 8;
        float4 u0 = *(const float4*)s;
        float4 u1 = *(const float4*)(s + 4);
        v = cvt8(u0, u1);
      } else {
        v = *(const f16x8*)(A1 + rowG * lda1 + (c - A0C) * 64 + eg * 8);
      }
      *(f16x8*)((char*)&sA[buf][0] + swz128((uint32_t)(row * 128 + eg * 16))) = v;
    }
  };

  f32x4 acc[RT][CT];
#pragma unroll
  for (int i = 0; i < RT; ++i)
#pragma unroll
    for (int j = 0; j < CT; ++j) acc[i][j] = (f32x4){0.f, 0.f, 0.f, 0.f};

  stageB(0, 0);
  stageA(0, 0);
  __syncthreads();

  for (int c = 0; c < NCHUNK; ++c) {
    int cur = c & 1;
    if (c + 1 < NCHUNK) {
      stageB(c + 1, cur ^ 1);
      stageA(c + 1, cur ^ 1);
    }
#pragma unroll
    for (int ks = 0; ks < 2; ++ks) {
      f16x8 af[RT], bf[CT];
#pragma unroll
      for (int rt = 0; rt < RT; ++rt) {
        int row = wr * (RT * 16) + rt * 16 + (lane & 15);
        af[rt] = *(const f16x8*)((const char*)&sA[cur][0] +
                                 swz128((uint32_t)(row * 128 + ks * 64 + (lane >> 4) * 16)));
      }
#pragma unroll
      for (int ct = 0; ct < CT; ++ct) {
        int col = wc * (CT * 16) + ct * 16 + (lane & 15);
        bf[ct] = *(const f16x8*)((const char*)&sB[cur][0] +
                                 swz128((uint32_t)(((ks * BN + col) * 4 + (lane >> 4)) * 16)));
      }
#pragma unroll
      for (int rt = 0; rt < RT; ++rt)
#pragma unroll
        for (int ct = 0; ct < CT; ++ct)
          acc[rt][ct] = __builtin_amdgcn_mfma_f32_16x16x32_f16(af[rt], bf[ct], acc[rt][ct], 0, 0, 0);
    }
    __syncthreads();
  }

#pragma unroll
  for (int rt = 0; rt < RT; ++rt)
#pragma unroll
    for (int ct = 0; ct < CT; ++ct)
#pragma unroll
      for (int i = 0; i < 4; ++i) {
        size_t row = (size_t)rb * 128 + wr * (RT * 16) + rt * 16 + (lane >> 4) * 4 + i;
        int colG = cb * BN + wc * (CT * 16) + ct * 16 + (lane & 15);
        float v = acc[rt][ct][i];
        if constexpr (EPI == 0) {
          if (bias) v += bias[colG];
          outF[row * ldo + colG] = v;
        } else {
          v += bias[colG];
          float ge = 0.5f * v * (1.0f + erff(v * 0.70710678118f));
          outH[row * ldo + colG] = (f16)ge;
        }
      }
}

// ---------------------------------------------------------------------------
// selector finish -> big_gemm staging layout:
// a16s[rb][g][row][j]  (rb = n>>8, row = n&255, m = g*8+j); 32KB per rb tile.
// ---------------------------------------------------------------------------
__global__ void selector_finish(const float* __restrict__ logits,
                                const float* __restrict__ glog,
                                const float* __restrict__ b2,
                                const float* __restrict__ vm,
                                f16* __restrict__ a16s) {
  int n = blockIdx.x * 4 + (threadIdx.x >> 6);
  int m = threadIdx.x & 63;
  float l = logits[(size_t)n * 64 + m] + b2[m];
  float mx = l;
#pragma unroll
  for (int o = 32; o; o >>= 1) mx = fmaxf(mx, __shfl_xor(mx, o));
  float p = expf(l - mx);
  float s = p;
#pragma unroll
  for (int o = 32; o; o >>= 1) s += __shfl_xor(s, o);
  float g = glog[(size_t)n * 64 + m] + vm[m];
  float gate = 1.0f / (1.0f + expf(-g));
  int rb = n >> 8, row = n & 255, gg = m >> 3, j = m & 7;
  a16s[(size_t)rb * 16384 + gg * 2048 + row * 8 + j] = (f16)(p / s * gate);
}

// ---------------------------------------------------------------------------
// big_gemm v7: barrier-free streaming. 256 threads (4 waves), tile 256x64,
// wave tile 64x64 (32x32x16, rt=2, ct=2). B-fragments: global->reg, named
// bf0/bf1 dbuf 2 chunks ahead. LDS: 32KB read-only a-tile only.
// Per chunk (static-unrolled): af = xv*a (VALU) -> 16 MFMA on bfX ->
// reload bfX <- chunk q+2 (8 x global_load_dwordx4, WAR-sequenced).
// ---------------------------------------------------------------------------
__global__ __launch_bounds__(256, 2)
void big_gemm(const float* __restrict__ x, const f16* __restrict__ a16s,
              const f16* __restrict__ Wcat, f16* __restrict__ sel) {
  __shared__ alignas(16) f16 sAa[8 * 256 * 8];   // 32 KB: [g][row 0..255][8m]

  const int tid = threadIdx.x;
  const int lane = tid & 63;
  const int wid = tid >> 6;        // 0..3 -> rows wid*64..+63
  const int l31 = lane & 31;
  const int khalf = lane >> 5;     // 0..1
  const int bid = blockIdx.x;
  const int xcd = bid & 7;
  const int cb = xcd >> 1;                      // col-quarter per XCD-pair
  const int rb = (xcd & 1) * 64 + (bid >> 3);   // 0..127 (256-row tiles)
  const char* Wb = (const char*)(Wcat + (size_t)cb * 260 * 4096);
  const int rbase = wid * 64 + l31;             // + rt*32

  // prologue: a-tile (32 KB) -> LDS, then ONE barrier; loop is barrier-free.
  {
    const char* aSrc = (const char*)(a16s + (size_t)rb * 16384);
#pragma unroll
    for (int it = 0; it < 8; ++it) {
      int off = (it * 256 + tid) * 16;
      gload_lds16(aSrc + off, (char*)sAa + off);
    }
  }
  asm volatile("s_waitcnt vmcnt(0)" ::: "memory");
  __builtin_amdgcn_s_barrier();

  // per-lane fragment offset within an 8 KB chunk: + ks*2048 + ct*512
  const int bOff = khalf * 1024 + l31 * 16;

  f32x16 acc[2][2];
#pragma unroll
  for (int i = 0; i < 2; ++i)
#pragma unroll
    for (int j = 0; j < 2; ++j)
#pragma unroll
      for (int r = 0; r < 16; ++r) acc[i][j][r] = 0.f;

  f16x8 xv[2][4];
  auto loadXV = [&](int er) {
#pragma unroll
    for (int rt = 0; rt < 2; ++rt)
#pragma unroll
      for (int ks = 0; ks < 4; ++ks) {
        const float* s = x + ((size_t)rb * 256 + rbase + rt * 32) * 256
                           + er * 64 + ks * 16 + khalf * 8;
        float4 u0 = *(const float4*)s;
        float4 u1 = *(const float4*)(s + 4);
        xv[rt][ks] = cvt8(u0, u1);
      }
  };
  loadXV(0);

  // B-fragment register double-buffer: bf0 = even chunks, bf1 = odd chunks.
  f16x8 bf0[8], bf1[8];
#pragma unroll
  for (int ks = 0; ks < 4; ++ks)
#pragma unroll
    for (int ct = 0; ct < 2; ++ct) {
      bf0[ks * 2 + ct] = *(const f16x8*)(Wb + 0 * 8192 + bOff + ks * 2048 + ct * 512);
      bf1[ks * 2 + ct] = *(const f16x8*)(Wb + 1 * 8192 + bOff + ks * 2048 + ct * 512);
    }

  for (int q8g = 0; q8g < 32; ++q8g) {
    const int q8 = q8g * 8;
    if ((q8 & 63) == 0 && q8 > 0) loadXV(q8 >> 6);
    // a-scalars for these 8 chunks: [g][row][8] conflict-free b128
    f16x8 as_cur[2];
    {
      int g = (q8 & 63) >> 3;
#pragma unroll
      for (int rt = 0; rt < 2; ++rt)
        as_cur[rt] = *(const f16x8*)((const char*)sAa + ((g * 256) + rbase + rt * 32) * 16);
    }
#pragma unroll
    for (int u = 0; u < 8; ++u) {
      const int q = q8 + u;
      f16x8 af[2][4];
#pragma unroll
      for (int rt = 0; rt < 2; ++rt)
#pragma unroll
        for (int ks = 0; ks < 4; ++ks)
          af[rt][ks] = xv[rt][ks] * as_cur[rt][u];
      const char* nsrc = Wb + (size_t)(q + 2) * 8192 + bOff;
      if ((u & 1) == 0) {
        __builtin_amdgcn_s_setprio(1);
#pragma unroll
        for (int ks = 0; ks < 4; ++ks)
#pragma unroll
          for (int rt = 0; rt < 2; ++rt)
#pragma unroll
            for (int ct = 0; ct < 2; ++ct)
              acc[rt][ct] = __builtin_amdgcn_mfma_f32_32x32x16_f16(
                  af[rt][ks], bf0[ks * 2 + ct], acc[rt][ct], 0, 0, 0);
        __builtin_amdgcn_s_setprio(0);
#pragma unroll
        for (int ks = 0; ks < 4; ++ks)
#pragma unroll
          for (int ct = 0; ct < 2; ++ct)
            bf0[ks * 2 + ct] = *(const f16x8*)(nsrc + ks * 2048 + ct * 512);
      } else {
        __builtin_amdgcn_s_setprio(1);
#pragma unroll
        for (int ks = 0; ks < 4; ++ks)
#pragma unroll
          for (int rt = 0; rt < 2; ++rt)
#pragma unroll
            for (int ct = 0; ct < 2; ++ct)
              acc[rt][ct] = __builtin_amdgcn_mfma_f32_32x32x16_f16(
                  af[rt][ks], bf1[ks * 2 + ct], acc[rt][ct], 0, 0, 0);
        __builtin_amdgcn_s_setprio(0);
#pragma unroll
        for (int ks = 0; ks < 4; ++ks)
#pragma unroll
          for (int ct = 0; ct < 2; ++ct)
            bf1[ks * 2 + ct] = *(const f16x8*)(nsrc + ks * 2048 + ct * 512);
      }
    }
  }

  // bias chunk (c=256): loaded into bf0 at q=254. A = a[row,k] from sAa.
#pragma unroll
  for (int ks = 0; ks < 4; ++ks)
#pragma unroll
    for (int rt = 0; rt < 2; ++rt) {
      int g = ks * 2 + khalf;
      f16x8 af = *(const f16x8*)((const char*)sAa + ((g * 256) + rbase + rt * 32) * 16);
#pragma unroll
      for (int ct = 0; ct < 2; ++ct)
        acc[rt][ct] = __builtin_amdgcn_mfma_f32_32x32x16_f16(
            af, bf0[ks * 2 + ct], acc[rt][ct], 0, 0, 0);
    }

  // store: row = rb*256 + wid*64 + rt*32 + (r&3)+8*(r>>2)+4*khalf;
  //        col = cb*64 + ct*32 + l31
#pragma unroll
  for (int rt = 0; rt < 2; ++rt)
#pragma unroll
    for (int ct = 0; ct < 2; ++ct)
#pragma unroll
      for (int r = 0; r < 16; ++r) {
        int rowin = (r & 3) + 8 * (r >> 2) + 4 * khalf;
        size_t row = (size_t)rb * 256 + wid * 64 + rt * 32 + rowin;
        int col = cb * 64 + ct * 32 + l31;
        sel[row * 256 + col] = (f16)acc[rt][ct][r];
      }
}

// ---------------------------------------------------------------------------
extern "C" void kernel_launch(void* const* d_in, const int* in_sizes, int n_in,
                              void* d_out, int out_size, void* d_ws, size_t ws_size,
                              hipStream_t stream) {
  (void)in_sizes; (void)n_in; (void)out_size;
  const float* x   = (const float*)d_in[0];
  const float* ctx = (const float*)d_in[1];
  const float* Wm  = (const float*)d_in[2];
  const float* bm  = (const float*)d_in[3];
  const float* cm  = (const float*)d_in[4];
  const float* um  = (const float*)d_in[5];
  const float* vm  = (const float*)d_in[6];
  const float* W1  = (const float*)d_in[7];
  const float* b1  = (const float*)d_in[8];
  const float* W2  = (const float*)d_in[9];
  const float* b2  = (const float*)d_in[10];
  const float* Wi  = (const float*)d_in[11];
  const float* bi  = (const float*)d_in[12];
  float* out = (float*)d_out;

  char* ws = (char*)d_ws;
  size_t off = 0;
  // Wcat: 4 col-quarters x 260 sub-chunk slots x 8KB
  f16* Wcat = (f16*)(ws + off); off += (size_t)4 * 260 * 4096 * 2;
  f16* W1t  = (f16*)(ws + off); off += (size_t)512 * 256 * 2;
  f16* W2t  = (f16*)(ws + off); off += (size_t)64 * 512 * 2;
  f16* umt  = (f16*)(ws + off); off += (size_t)64 * 256 * 2;
  f16* Wit  = (f16*)(ws + off); off += (size_t)256 * 512 * 2;
  f16* h16  = (f16*)(ws + off); off += (size_t)32768 * 512 * 2;
  float* logits = (float*)(ws + off); off += (size_t)32768 * 64 * 4;
  float* glog   = (float*)(ws + off); off += (size_t)32768 * 64 * 4;
  f16* a16s  = (f16*)(ws + off); off += (size_t)32768 * 64 * 2;
  f16* sel16 = (f16*)(ws + off); off += (size_t)32768 * 256 * 2;
  if (ws_size < off) return;

  // ---- weight prep ----
  prep_wcat_kernel<<<dim3(2056), dim3(256), 0, stream>>>(Wm, bm, cm, Wcat);
  prep_b_kernel<<<dim3(16384 / 256), dim3(256), 0, stream>>>(W1, W1t, 256, 256, 16384);
  prep_b_kernel<<<dim3(4096 / 256),  dim3(256), 0, stream>>>(W2, W2t, 512, 64, 4096);
  prep_b_kernel<<<dim3(2048 / 256),  dim3(256), 0, stream>>>(um, umt, 256, 64, 2048);
  prep_b_kernel<<<dim3(16384 / 256), dim3(256), 0, stream>>>(Wi, Wit, 512, 256, 16384);

  // ---- phase A: selector ----
  gemm_tpl<256, 4, 4, 1><<<dim3(256, 2), dim3(512), 0, stream>>>(
      ctx, 256, nullptr, 0, W1t, b1, nullptr, h16, 512);
  gemm_tpl<64, 4, 4, 0><<<dim3(256, 1), dim3(256), 0, stream>>>(
      x, 256, nullptr, 0, umt, nullptr, glog, nullptr, 64);
  gemm_tpl<64, 8, 0, 0><<<dim3(256, 1), dim3(256), 0, stream>>>(
      nullptr, 0, h16, 512, W2t, nullptr, logits, nullptr, 64);
  selector_finish<<<dim3(32768 / 4), dim3(256), 0, stream>>>(logits, glog, b2, vm, a16s);

  // ---- phase B: the 275-TFLOP contraction ----
  big_gemm<<<dim3(512), dim3(256), 0, stream>>>(x, a16s, Wcat, sel16);

  // ---- phase C: integrate([x, selected]) ----
  gemm_tpl<256, 8, 4, 0><<<dim3(256, 1), dim3(512), 0, stream>>>(
      x, 256, sel16, 256, Wit, bi, out, nullptr, 256);
}

// Round 10
// 363.351 us; speedup vs baseline: 1.0355x; 1.0355x over previous
//
#include <hip/hip_runtime.h>
#include <cstdint>
#include <cstddef>

// ============================================================================
// MechanismGrabber on MI355X (gfx950)
//
// selected[n,d] = sum_{m,e} a[n,m]*x[n,e]*Wm[m,d,e] + sum_m a[n,m]*(bm+cm)[m,d]
// == single GEMM: (N=32768) x (K=16448) x (D=256) with A generated on the fly.
//
// R9: m201-style phase discipline + 4 waves/SIMD.
//     8-wave blocks (512thr), tile 256x64, wave tile 64x32 (rt=2,ct=1),
//     2 blocks/CU (launch_bounds(512,4) caps VGPR at 128). Ring-of-4 8KB
//     slots (static q&3 indexing). Per chunk-phase:
//     {ds_read bf(q) | stage(q+2) -> vmcnt(1) -> barrier -> lgkmcnt(0) ->
//      setprio(1) 8 MFMA w/ inline af muls setprio(0) -> barrier}.
// ============================================================================

typedef _Float16 f16;
typedef f16 f16x8 __attribute__((ext_vector_type(8)));
typedef float f32x4 __attribute__((ext_vector_type(4)));
typedef float f32x16 __attribute__((ext_vector_type(16)));

#define DEV __device__ __forceinline__

DEV uint32_t swz128(uint32_t b) { return b ^ (((b >> 7) & 7u) << 4); }

DEV void gload_lds16(const void* g, void* l) {
  __builtin_amdgcn_global_load_lds(
      (const __attribute__((address_space(1))) unsigned int*)g,
      (__attribute__((address_space(3))) unsigned int*)l, 16, 0, 0);
}

DEV f16x8 cvt8(float4 u0, float4 u1) {
  f16x8 v = {(f16)u0.x, (f16)u0.y, (f16)u0.z, (f16)u0.w,
             (f16)u1.x, (f16)u1.y, (f16)u1.z, (f16)u1.w};
  return v;
}

// ---------------------------------------------------------------------------
// prep for gemm_tpl (16x16x32 path, selector/integrate): unchanged.
// ---------------------------------------------------------------------------
__global__ void prep_b_kernel(const float* __restrict__ S, f16* __restrict__ dst,
                              int K, int BN, int total) {
  int t = blockIdx.x * 256 + threadIdx.x;
  if (t >= total) return;
  int gpc = BN * 8;
  int g = t % gpc;
  int c = (t / gpc) % (K / 64);
  int cb = t / (gpc * (K / 64));
  int ks = g / (BN * 4);
  int rem = g % (BN * 4);
  int col = rem >> 2;
  int kg = rem & 3;
  int J = cb * BN + col;
  int k = c * 64 + ks * 32 + kg * 8;
  const float* s = S + (size_t)J * K + k;
  float4 u0 = *(const float4*)s;
  float4 u1 = *(const float4*)(s + 4);
  f16* chunk = dst + (size_t)(cb * (K / 64) + c) * (BN * 64);
  *(f16x8*)((char*)chunk + swz128((uint32_t)g * 16)) = cvt8(u0, u1);
}

// ---------------------------------------------------------------------------
// Wcat: [cb 0..3][c 0..259] sub-chunks of 64k x 64col = 8 KB (linear,
// per-lane fragment-contiguous). group g = kstep*128 + khalf*64 + col64,
// byte g*16, holds B[k][col] for k = kstep*16 + khalf*8 + (0..7),
// col = cb*64 + col64.
// c<256: er=c>>6, m=c&63; value[k][col] = Wm[m][col][er*64+k].
// c==256: value[k][col] = bm[k][col]+cm[k][col].  c>=257: dummy.
// ---------------------------------------------------------------------------
__global__ void prep_wcat_kernel(const float* __restrict__ Wm,
                                 const float* __restrict__ bm,
                                 const float* __restrict__ cm,
                                 f16* __restrict__ dst) {
  int t = blockIdx.x * 256 + threadIdx.x;
  if (t >= 4 * 257 * 512) return;
  int g = t & 511;
  int gc = t >> 9;
  int c = gc % 257;
  int cb = gc / 257;
  int kstep = g >> 7;          // 0..3
  int khalf = (g >> 6) & 1;    // 0..1
  int col = cb * 64 + (g & 63);
  int k0 = kstep * 16 + khalf * 8;
  f16x8 v;
  if (c < 256) {
    int m = c & 63;
    int e0 = (c >> 6) * 64 + k0;
    const float* s = Wm + ((size_t)m * 256 + col) * 256 + e0;
    float4 u0 = *(const float4*)s;
    float4 u1 = *(const float4*)(s + 4);
    v = cvt8(u0, u1);
  } else {
#pragma unroll
    for (int j = 0; j < 8; ++j) {
      int k = k0 + j;
      v[j] = (f16)(bm[k * 256 + col] + cm[k * 256 + col]);
    }
  }
  *(f16x8*)(dst + ((size_t)(cb * 260 + c)) * 4096 + (size_t)g * 8) = v;
}

// ---------------------------------------------------------------------------
// Generic MFMA GEMM (selector + integrate phases). Unchanged.
// ---------------------------------------------------------------------------
template <int BN, int NCHUNK, int A0C, int EPI>
__global__ __launch_bounds__(BN == 256 ? 512 : 256, 2)
void gemm_tpl(const float* __restrict__ A0, int lda0,
              const f16* __restrict__ A1, int lda1,
              const f16* __restrict__ Bt,
              const float* __restrict__ bias,
              float* __restrict__ outF, f16* __restrict__ outH, int ldo) {
  constexpr int WAVES = (BN == 256) ? 8 : 4;
  constexpr int THREADS = WAVES * 64;
  constexpr int WC = (BN == 256) ? 4 : 1;
  constexpr int WR = WAVES / WC;
  constexpr int RT = 128 / (WR * 16);
  constexpr int CT = (BN / WC) / 16;

  __shared__ alignas(16) f16 sA[2][128 * 64];
  __shared__ alignas(16) f16 sB[2][BN * 64];

  const int tid = threadIdx.x;
  const int lane = tid & 63;
  const int wid = tid >> 6;
  const int wr = wid / WC, wc = wid % WC;
  const int rb = blockIdx.x, cb = blockIdx.y;

  auto stageB = [&](int c, int buf) {
    const char* src = (const char*)(Bt + (size_t)(cb * NCHUNK + c) * (BN * 64));
#pragma unroll
    for (int it = 0; it < (BN * 64 * 2) / (THREADS * 16); ++it) {
      int off = (it * THREADS + tid) * 16;
      gload_lds16(src + off, (char*)&sB[buf][0] + off);
    }
  };
  auto stageA = [&](int c, int buf) {
#pragma unroll
    for (int it = 0; it < 1024 / THREADS; ++it) {
      int gg = it * THREADS + tid;
      int row = gg >> 3, eg = gg & 7;
      size_t rowG = (size_t)rb * 128 + row;
      f16x8 v;
      if (A0C > 0 && c < A0C) {
        const float* s = A0 + rowG * lda0 + c * 64 + eg * 8;
        float4 u0 = *(const float4*)s;
        float4 u1 = *(const float4*)(s + 4);
        v = cvt8(u0, u1);
      } else {
        v = *(const f16x8*)(A1 + rowG * lda1 + (c - A0C) * 64 + eg * 8);
      }
      *(f16x8*)((char*)&sA[buf][0] + swz128((uint32_t)(row * 128 + eg * 16))) = v;
    }
  };

  f32x4 acc[RT][CT];
#pragma unroll
  for (int i = 0; i < RT; ++i)
#pragma unroll
    for (int j = 0; j < CT; ++j) acc[i][j] = (f32x4){0.f, 0.f, 0.f, 0.f};

  stageB(0, 0);
  stageA(0, 0);
  __syncthreads();

  for (int c = 0; c < NCHUNK; ++c) {
    int cur = c & 1;
    if (c + 1 < NCHUNK) {
      stageB(c + 1, cur ^ 1);
      stageA(c + 1, cur ^ 1);
    }
#pragma unroll
    for (int ks = 0; ks < 2; ++ks) {
      f16x8 af[RT], bf[CT];
#pragma unroll
      for (int rt = 0; rt < RT; ++rt) {
        int row = wr * (RT * 16) + rt * 16 + (lane & 15);
        af[rt] = *(const f16x8*)((const char*)&sA[cur][0] +
                                 swz128((uint32_t)(row * 128 + ks * 64 + (lane >> 4) * 16)));
      }
#pragma unroll
      for (int ct = 0; ct < CT; ++ct) {
        int col = wc * (CT * 16) + ct * 16 + (lane & 15);
        bf[ct] = *(const f16x8*)((const char*)&sB[cur][0] +
                                 swz128((uint32_t)(((ks * BN + col) * 4 + (lane >> 4)) * 16)));
      }
#pragma unroll
      for (int rt = 0; rt < RT; ++rt)
#pragma unroll
        for (int ct = 0; ct < CT; ++ct)
          acc[rt][ct] = __builtin_amdgcn_mfma_f32_16x16x32_f16(af[rt], bf[ct], acc[rt][ct], 0, 0, 0);
    }
    __syncthreads();
  }

#pragma unroll
  for (int rt = 0; rt < RT; ++rt)
#pragma unroll
    for (int ct = 0; ct < CT; ++ct)
#pragma unroll
      for (int i = 0; i < 4; ++i) {
        size_t row = (size_t)rb * 128 + wr * (RT * 16) + rt * 16 + (lane >> 4) * 4 + i;
        int colG = cb * BN + wc * (CT * 16) + ct * 16 + (lane & 15);
        float v = acc[rt][ct][i];
        if constexpr (EPI == 0) {
          if (bias) v += bias[colG];
          outF[row * ldo + colG] = v;
        } else {
          v += bias[colG];
          float ge = 0.5f * v * (1.0f + erff(v * 0.70710678118f));
          outH[row * ldo + colG] = (f16)ge;
        }
      }
}

// ---------------------------------------------------------------------------
// selector finish -> big_gemm staging layout:
// a16s[rb][g][row][j]  (rb = n>>8, row = n&255, m = g*8+j); 32KB per rb tile.
// ---------------------------------------------------------------------------
__global__ void selector_finish(const float* __restrict__ logits,
                                const float* __restrict__ glog,
                                const float* __restrict__ b2,
                                const float* __restrict__ vm,
                                f16* __restrict__ a16s) {
  int n = blockIdx.x * 4 + (threadIdx.x >> 6);
  int m = threadIdx.x & 63;
  float l = logits[(size_t)n * 64 + m] + b2[m];
  float mx = l;
#pragma unroll
  for (int o = 32; o; o >>= 1) mx = fmaxf(mx, __shfl_xor(mx, o));
  float p = expf(l - mx);
  float s = p;
#pragma unroll
  for (int o = 32; o; o >>= 1) s += __shfl_xor(s, o);
  float g = glog[(size_t)n * 64 + m] + vm[m];
  float gate = 1.0f / (1.0f + expf(-g));
  int rb = n >> 8, row = n & 255, gg = m >> 3, j = m & 7;
  a16s[(size_t)rb * 16384 + gg * 2048 + row * 8 + j] = (f16)(p / s * gate);
}

// ---------------------------------------------------------------------------
// big_gemm v8: m201-phase schedule. 512 thr (8 waves, wr=wid>>1, wc=wid&1),
// tile 256x64, wave tile 64x32 (rt=2, ct=1, 8 MFMA/wave/chunk).
// LDS: 4x8KB ring (static q&3) + 32KB a-tile = 64KB -> 2 blocks/CU,
// launch_bounds(512,4) -> VGPR<=128 -> 4 waves/SIMD.
// ---------------------------------------------------------------------------
__global__ __launch_bounds__(512, 4)
void big_gemm(const float* __restrict__ x, const f16* __restrict__ a16s,
              const f16* __restrict__ Wcat, f16* __restrict__ sel) {
  __shared__ alignas(16) f16 sB[4][64 * 64];     // 4 x 8 KB ring
  __shared__ alignas(16) f16 sAa[8 * 256 * 8];   // 32 KB: [g][row 0..255][8m]

  const int tid = threadIdx.x;
  const int lane = tid & 63;
  const int wid = tid >> 6;        // 0..7
  const int wr = wid >> 1;         // 0..3 -> rows wr*64..+63
  const int wc = wid & 1;          // 0..1 -> cols wc*32..+31
  const int l31 = lane & 31;
  const int khalf = lane >> 5;     // 0..1
  const int bid = blockIdx.x;
  const int xcd = bid & 7;
  const int cb = xcd >> 1;                      // col-quarter per XCD-pair
  const int rb = (xcd & 1) * 64 + (bid >> 3);   // 0..127 (256-row tiles)
  const char* Wb = (const char*)(Wcat + (size_t)cb * 260 * 4096);
  const int rbase = wr * 64 + l31;              // + rt*32

  char* const sBb = (char*)&sB[0][0];

  auto stageChunk = [&](int c, int slotIdx) {   // 8 KB, 1 load/thread
    gload_lds16(Wb + (size_t)c * 8192 + tid * 16, sBb + slotIdx * 8192 + tid * 16);
  };

  // prologue: a-tile (32 KB, 4 loads/thread) + chunks 0,1
  {
    const char* aSrc = (const char*)(a16s + (size_t)rb * 16384);
#pragma unroll
    for (int it = 0; it < 4; ++it) {
      int off = (it * 512 + tid) * 16;
      gload_lds16(aSrc + off, (char*)sAa + off);
    }
  }
  stageChunk(0, 0);
  stageChunk(1, 1);
  asm volatile("s_waitcnt vmcnt(0)" ::: "memory");
  __builtin_amdgcn_s_barrier();

  f32x16 acc[2];
#pragma unroll
  for (int rt = 0; rt < 2; ++rt)
#pragma unroll
    for (int r = 0; r < 16; ++r) acc[rt][r] = 0.f;

  f16x8 xv[2][4];
  auto loadXV = [&](int er) {
#pragma unroll
    for (int rt = 0; rt < 2; ++rt)
#pragma unroll
      for (int ks = 0; ks < 4; ++ks) {
        const float* s = x + ((size_t)rb * 256 + rbase + rt * 32) * 256
                           + er * 64 + ks * 16 + khalf * 8;
        float4 u0 = *(const float4*)s;
        float4 u1 = *(const float4*)(s + 4);
        xv[rt][ks] = cvt8(u0, u1);
      }
  };

  // per-lane B offset within an 8 KB chunk: + ks*2048
  const int bOff = khalf * 1024 + wc * 512 + l31 * 16;

  f16x8 as8[2];

  for (int q8g = 0; q8g < 32; ++q8g) {
    const int q8 = q8g * 8;
#pragma unroll
    for (int u = 0; u < 8; ++u) {
      const int q = q8 + u;
      if (u == 0) {
        if ((q8 & 63) == 0) loadXV(q8 >> 6);    // 16 vm loads; drained by vmcnt(1)
        int g = (q8 & 63) >> 3;
#pragma unroll
        for (int rt = 0; rt < 2; ++rt)
          as8[rt] = *(const f16x8*)((const char*)sAa + ((g * 256) + rbase + rt * 32) * 16);
      }
      // ---- pre-barrier region: this chunk's B reads + stage(q+2) ----
      const char* slotB = sBb + (size_t)((q8g * 8 + u) & 3) * 8192 + bOff;
      f16x8 bf[4];
#pragma unroll
      for (int ks = 0; ks < 4; ++ks)
        bf[ks] = *(const f16x8*)(slotB + ks * 2048);
      stageChunk(q + 2, (u + 2) & 3);           // q&3 == u&3 (q8 % 4 == 0)
      asm volatile("s_waitcnt vmcnt(1)" ::: "memory");  // chunk q+1 landed (own)
      __builtin_amdgcn_s_barrier();                      // ... globally
      asm volatile("s_waitcnt lgkmcnt(0)" ::: "memory"); // bf in regs
      __builtin_amdgcn_sched_barrier(0);
      // ---- MFMA cluster ----
      __builtin_amdgcn_s_setprio(1);
#pragma unroll
      for (int ks = 0; ks < 4; ++ks)
#pragma unroll
        for (int rt = 0; rt < 2; ++rt) {
          f16x8 af = xv[rt][ks] * as8[rt][u];
          acc[rt] = __builtin_amdgcn_mfma_f32_32x32x16_f16(af, bf[ks], acc[rt], 0, 0, 0);
        }
      __builtin_amdgcn_s_setprio(0);
      __builtin_amdgcn_sched_barrier(0);
      __builtin_amdgcn_s_barrier();
    }
  }

  // bias chunk (q=256, slot 0): certified by phase 255's vmcnt(1)+barrier.
  {
    const char* slotB = sBb + 0 * 8192 + bOff;
    f16x8 bf[4];
#pragma unroll
    for (int ks = 0; ks < 4; ++ks)
      bf[ks] = *(const f16x8*)(slotB + ks * 2048);
    asm volatile("s_waitcnt lgkmcnt(0)" ::: "memory");
    __builtin_amdgcn_sched_barrier(0);
#pragma unroll
    for (int ks = 0; ks < 4; ++ks)
#pragma unroll
      for (int rt = 0; rt < 2; ++rt) {
        int g = ks * 2 + khalf;
        f16x8 af = *(const f16x8*)((const char*)sAa + ((g * 256) + rbase + rt * 32) * 16);
        acc[rt] = __builtin_amdgcn_mfma_f32_32x32x16_f16(af, bf[ks], acc[rt], 0, 0, 0);
      }
  }

  // store: row = rb*256 + wr*64 + rt*32 + (r&3)+8*(r>>2)+4*khalf;
  //        col = cb*64 + wc*32 + l31
#pragma unroll
  for (int rt = 0; rt < 2; ++rt)
#pragma unroll
    for (int r = 0; r < 16; ++r) {
      int rowin = (r & 3) + 8 * (r >> 2) + 4 * khalf;
      size_t row = (size_t)rb * 256 + wr * 64 + rt * 32 + rowin;
      int col = cb * 64 + wc * 32 + l31;
      sel[row * 256 + col] = (f16)acc[rt][r];
    }
}

// ---------------------------------------------------------------------------
extern "C" void kernel_launch(void* const* d_in, const int* in_sizes, int n_in,
                              void* d_out, int out_size, void* d_ws, size_t ws_size,
                              hipStream_t stream) {
  (void)in_sizes; (void)n_in; (void)out_size;
  const float* x   = (const float*)d_in[0];
  const float* ctx = (const float*)d_in[1];
  const float* Wm  = (const float*)d_in[2];
  const float* bm  = (const float*)d_in[3];
  const float* cm  = (const float*)d_in[4];
  const float* um  = (const float*)d_in[5];
  const float* vm  = (const float*)d_in[6];
  const float* W1  = (const float*)d_in[7];
  const float* b1  = (const float*)d_in[8];
  const float* W2  = (const float*)d_in[9];
  const float* b2  = (const float*)d_in[10];
  const float* Wi  = (const float*)d_in[11];
  const float* bi  = (const float*)d_in[12];
  float* out = (float*)d_out;

  char* ws = (char*)d_ws;
  size_t off = 0;
  // Wcat: 4 col-quarters x 260 sub-chunk slots x 8KB
  f16* Wcat = (f16*)(ws + off); off += (size_t)4 * 260 * 4096 * 2;
  f16* W1t  = (f16*)(ws + off); off += (size_t)512 * 256 * 2;
  f16* W2t  = (f16*)(ws + off); off += (size_t)64 * 512 * 2;
  f16* umt  = (f16*)(ws + off); off += (size_t)64 * 256 * 2;
  f16* Wit  = (f16*)(ws + off); off += (size_t)256 * 512 * 2;
  f16* h16  = (f16*)(ws + off); off += (size_t)32768 * 512 * 2;
  float* logits = (float*)(ws + off); off += (size_t)32768 * 64 * 4;
  float* glog   = (float*)(ws + off); off += (size_t)32768 * 64 * 4;
  f16* a16s  = (f16*)(ws + off); off += (size_t)32768 * 64 * 2;
  f16* sel16 = (f16*)(ws + off); off += (size_t)32768 * 256 * 2;
  if (ws_size < off) return;

  // ---- weight prep ----
  prep_wcat_kernel<<<dim3(2056), dim3(256), 0, stream>>>(Wm, bm, cm, Wcat);
  prep_b_kernel<<<dim3(16384 / 256), dim3(256), 0, stream>>>(W1, W1t, 256, 256, 16384);
  prep_b_kernel<<<dim3(4096 / 256),  dim3(256), 0, stream>>>(W2, W2t, 512, 64, 4096);
  prep_b_kernel<<<dim3(2048 / 256),  dim3(256), 0, stream>>>(um, umt, 256, 64, 2048);
  prep_b_kernel<<<dim3(16384 / 256), dim3(256), 0, stream>>>(Wi, Wit, 512, 256, 16384);

  // ---- phase A: selector ----
  gemm_tpl<256, 4, 4, 1><<<dim3(256, 2), dim3(512), 0, stream>>>(
      ctx, 256, nullptr, 0, W1t, b1, nullptr, h16, 512);
  gemm_tpl<64, 4, 4, 0><<<dim3(256, 1), dim3(256), 0, stream>>>(
      x, 256, nullptr, 0, umt, nullptr, glog, nullptr, 64);
  gemm_tpl<64, 8, 0, 0><<<dim3(256, 1), dim3(256), 0, stream>>>(
      nullptr, 0, h16, 512, W2t, nullptr, logits, nullptr, 64);
  selector_finish<<<dim3(32768 / 4), dim3(256), 0, stream>>>(logits, glog, b2, vm, a16s);

  // ---- phase B: the 275-TFLOP contraction ----
  big_gemm<<<dim3(512), dim3(512), 0, stream>>>(x, a16s, Wcat, sel16);

  // ---- phase C: integrate([x, selected]) ----
  gemm_tpl<256, 8, 4, 0><<<dim3(256, 1), dim3(512), 0, stream>>>(
      x, 256, sel16, 256, Wit, bi, out, nullptr, 256);
}

// Round 11
// 345.451 us; speedup vs baseline: 1.0891x; 1.0518x over previous
//
#include <hip/hip_runtime.h>
#include <cstdint>
#include <cstddef>

// ============================================================================
// MechanismGrabber on MI355X (gfx950)
//
// selected[n,d] = sum_{m,e} a[n,m]*x[n,e]*Wm[m,d,e] + sum_m a[n,m]*(bm+cm)[m,d]
// == single GEMM: (N=32768) x (K=16448) x (D=256) with A generated on the fly.
//
// R10: FAT WAVES. 2-wave blocks (128 thr), wave tile 128x64 (rt=4, ct=2),
//      block tile 256x64, 2 blocks/CU -> 1 wave/SIMD. Each wave owns
//      32 MFMA/chunk (~1088 cy of matrix pipe) vs ~130 cy of own overhead:
//      in-order issue interleaves VALU/LDS into MFMA gaps. Ring-of-4 8KB
//      slots, stage distance 2, vmcnt(4)->barrier->stage->8 ds_read->32 MFMA.
// ============================================================================

typedef _Float16 f16;
typedef f16 f16x8 __attribute__((ext_vector_type(8)));
typedef float f32x4 __attribute__((ext_vector_type(4)));
typedef float f32x16 __attribute__((ext_vector_type(16)));

#define DEV __device__ __forceinline__

DEV uint32_t swz128(uint32_t b) { return b ^ (((b >> 7) & 7u) << 4); }

DEV void gload_lds16(const void* g, void* l) {
  __builtin_amdgcn_global_load_lds(
      (const __attribute__((address_space(1))) unsigned int*)g,
      (__attribute__((address_space(3))) unsigned int*)l, 16, 0, 0);
}

DEV f16x8 cvt8(float4 u0, float4 u1) {
  f16x8 v = {(f16)u0.x, (f16)u0.y, (f16)u0.z, (f16)u0.w,
             (f16)u1.x, (f16)u1.y, (f16)u1.z, (f16)u1.w};
  return v;
}

// ---------------------------------------------------------------------------
// prep for gemm_tpl (16x16x32 path, selector/integrate): unchanged.
// ---------------------------------------------------------------------------
__global__ void prep_b_kernel(const float* __restrict__ S, f16* __restrict__ dst,
                              int K, int BN, int total) {
  int t = blockIdx.x * 256 + threadIdx.x;
  if (t >= total) return;
  int gpc = BN * 8;
  int g = t % gpc;
  int c = (t / gpc) % (K / 64);
  int cb = t / (gpc * (K / 64));
  int ks = g / (BN * 4);
  int rem = g % (BN * 4);
  int col = rem >> 2;
  int kg = rem & 3;
  int J = cb * BN + col;
  int k = c * 64 + ks * 32 + kg * 8;
  const float* s = S + (size_t)J * K + k;
  float4 u0 = *(const float4*)s;
  float4 u1 = *(const float4*)(s + 4);
  f16* chunk = dst + (size_t)(cb * (K / 64) + c) * (BN * 64);
  *(f16x8*)((char*)chunk + swz128((uint32_t)g * 16)) = cvt8(u0, u1);
}

// ---------------------------------------------------------------------------
// Wcat: [cb 0..3][c 0..259] sub-chunks of 64k x 64col = 8 KB (linear,
// per-lane fragment-contiguous). group g = kstep*128 + khalf*64 + col64,
// byte g*16, holds B[k][col] for k = kstep*16 + khalf*8 + (0..7),
// col = cb*64 + col64.
// c<256: er=c>>6, m=c&63; value[k][col] = Wm[m][col][er*64+k].
// c==256: value[k][col] = bm[k][col]+cm[k][col].  c>=257: dummy.
// ---------------------------------------------------------------------------
__global__ void prep_wcat_kernel(const float* __restrict__ Wm,
                                 const float* __restrict__ bm,
                                 const float* __restrict__ cm,
                                 f16* __restrict__ dst) {
  int t = blockIdx.x * 256 + threadIdx.x;
  if (t >= 4 * 257 * 512) return;
  int g = t & 511;
  int gc = t >> 9;
  int c = gc % 257;
  int cb = gc / 257;
  int kstep = g >> 7;          // 0..3
  int khalf = (g >> 6) & 1;    // 0..1
  int col = cb * 64 + (g & 63);
  int k0 = kstep * 16 + khalf * 8;
  f16x8 v;
  if (c < 256) {
    int m = c & 63;
    int e0 = (c >> 6) * 64 + k0;
    const float* s = Wm + ((size_t)m * 256 + col) * 256 + e0;
    float4 u0 = *(const float4*)s;
    float4 u1 = *(const float4*)(s + 4);
    v = cvt8(u0, u1);
  } else {
#pragma unroll
    for (int j = 0; j < 8; ++j) {
      int k = k0 + j;
      v[j] = (f16)(bm[k * 256 + col] + cm[k * 256 + col]);
    }
  }
  *(f16x8*)(dst + ((size_t)(cb * 260 + c)) * 4096 + (size_t)g * 8) = v;
}

// ---------------------------------------------------------------------------
// Generic MFMA GEMM (selector + integrate phases). Unchanged.
// ---------------------------------------------------------------------------
template <int BN, int NCHUNK, int A0C, int EPI>
__global__ __launch_bounds__(BN == 256 ? 512 : 256, 2)
void gemm_tpl(const float* __restrict__ A0, int lda0,
              const f16* __restrict__ A1, int lda1,
              const f16* __restrict__ Bt,
              const float* __restrict__ bias,
              float* __restrict__ outF, f16* __restrict__ outH, int ldo) {
  constexpr int WAVES = (BN == 256) ? 8 : 4;
  constexpr int THREADS = WAVES * 64;
  constexpr int WC = (BN == 256) ? 4 : 1;
  constexpr int WR = WAVES / WC;
  constexpr int RT = 128 / (WR * 16);
  constexpr int CT = (BN / WC) / 16;

  __shared__ alignas(16) f16 sA[2][128 * 64];
  __shared__ alignas(16) f16 sB[2][BN * 64];

  const int tid = threadIdx.x;
  const int lane = tid & 63;
  const int wid = tid >> 6;
  const int wr = wid / WC, wc = wid % WC;
  const int rb = blockIdx.x, cb = blockIdx.y;

  auto stageB = [&](int c, int buf) {
    const char* src = (const char*)(Bt + (size_t)(cb * NCHUNK + c) * (BN * 64));
#pragma unroll
    for (int it = 0; it < (BN * 64 * 2) / (THREADS * 16); ++it) {
      int off = (it * THREADS + tid) * 16;
      gload_lds16(src + off, (char*)&sB[buf][0] + off);
    }
  };
  auto stageA = [&](int c, int buf) {
#pragma unroll
    for (int it = 0; it < 1024 / THREADS; ++it) {
      int gg = it * THREADS + tid;
      int row = gg >> 3, eg = gg & 7;
      size_t rowG = (size_t)rb * 128 + row;
      f16x8 v;
      if (A0C > 0 && c < A0C) {
        const float* s = A0 + rowG * lda0 + c * 64 + eg * 8;
        float4 u0 = *(const float4*)s;
        float4 u1 = *(const float4*)(s + 4);
        v = cvt8(u0, u1);
      } else {
        v = *(const f16x8*)(A1 + rowG * lda1 + (c - A0C) * 64 + eg * 8);
      }
      *(f16x8*)((char*)&sA[buf][0] + swz128((uint32_t)(row * 128 + eg * 16))) = v;
    }
  };

  f32x4 acc[RT][CT];
#pragma unroll
  for (int i = 0; i < RT; ++i)
#pragma unroll
    for (int j = 0; j < CT; ++j) acc[i][j] = (f32x4){0.f, 0.f, 0.f, 0.f};

  stageB(0, 0);
  stageA(0, 0);
  __syncthreads();

  for (int c = 0; c < NCHUNK; ++c) {
    int cur = c & 1;
    if (c + 1 < NCHUNK) {
      stageB(c + 1, cur ^ 1);
      stageA(c + 1, cur ^ 1);
    }
#pragma unroll
    for (int ks = 0; ks < 2; ++ks) {
      f16x8 af[RT], bf[CT];
#pragma unroll
      for (int rt = 0; rt < RT; ++rt) {
        int row = wr * (RT * 16) + rt * 16 + (lane & 15);
        af[rt] = *(const f16x8*)((const char*)&sA[cur][0] +
                                 swz128((uint32_t)(row * 128 + ks * 64 + (lane >> 4) * 16)));
      }
#pragma unroll
      for (int ct = 0; ct < CT; ++ct) {
        int col = wc * (CT * 16) + ct * 16 + (lane & 15);
        bf[ct] = *(const f16x8*)((const char*)&sB[cur][0] +
                                 swz128((uint32_t)(((ks * BN + col) * 4 + (lane >> 4)) * 16)));
      }
#pragma unroll
      for (int rt = 0; rt < RT; ++rt)
#pragma unroll
        for (int ct = 0; ct < CT; ++ct)
          acc[rt][ct] = __builtin_amdgcn_mfma_f32_16x16x32_f16(af[rt], bf[ct], acc[rt][ct], 0, 0, 0);
    }
    __syncthreads();
  }

#pragma unroll
  for (int rt = 0; rt < RT; ++rt)
#pragma unroll
    for (int ct = 0; ct < CT; ++ct)
#pragma unroll
      for (int i = 0; i < 4; ++i) {
        size_t row = (size_t)rb * 128 + wr * (RT * 16) + rt * 16 + (lane >> 4) * 4 + i;
        int colG = cb * BN + wc * (CT * 16) + ct * 16 + (lane & 15);
        float v = acc[rt][ct][i];
        if constexpr (EPI == 0) {
          if (bias) v += bias[colG];
          outF[row * ldo + colG] = v;
        } else {
          v += bias[colG];
          float ge = 0.5f * v * (1.0f + erff(v * 0.70710678118f));
          outH[row * ldo + colG] = (f16)ge;
        }
      }
}

// ---------------------------------------------------------------------------
// selector finish -> big_gemm staging layout:
// a16s[rb][g][row][j]  (rb = n>>8, row = n&255, m = g*8+j); 32KB per rb tile.
// ---------------------------------------------------------------------------
__global__ void selector_finish(const float* __restrict__ logits,
                                const float* __restrict__ glog,
                                const float* __restrict__ b2,
                                const float* __restrict__ vm,
                                f16* __restrict__ a16s) {
  int n = blockIdx.x * 4 + (threadIdx.x >> 6);
  int m = threadIdx.x & 63;
  float l = logits[(size_t)n * 64 + m] + b2[m];
  float mx = l;
#pragma unroll
  for (int o = 32; o; o >>= 1) mx = fmaxf(mx, __shfl_xor(mx, o));
  float p = expf(l - mx);
  float s = p;
#pragma unroll
  for (int o = 32; o; o >>= 1) s += __shfl_xor(s, o);
  float g = glog[(size_t)n * 64 + m] + vm[m];
  float gate = 1.0f / (1.0f + expf(-g));
  int rb = n >> 8, row = n & 255, gg = m >> 3, j = m & 7;
  a16s[(size_t)rb * 16384 + gg * 2048 + row * 8 + j] = (f16)(p / s * gate);
}

// ---------------------------------------------------------------------------
// big_gemm v9 (fat waves): 128 thr = 2 waves, block tile 256x64, wave tile
// 128x64 (rt=4, ct=2; 32 MFMA 32x32x16 per wave per chunk). LDS: 4x8KB ring
// + 32KB a-tile = 64KB -> 2 blocks/CU -> 1 wave/SIMD. Per chunk:
// vmcnt(4) -> barrier -> sched_barrier -> stage(q+2) -> 8 ds_read_b128 ->
// 32 MFMA with af-muls inline (compiler interleaves into MFMA issue gaps).
// ---------------------------------------------------------------------------
__global__ __launch_bounds__(128)
void big_gemm(const float* __restrict__ x, const f16* __restrict__ a16s,
              const f16* __restrict__ Wcat, f16* __restrict__ sel) {
  __shared__ alignas(16) f16 sB[4][64 * 64];     // 4 x 8 KB ring
  __shared__ alignas(16) f16 sAa[8 * 256 * 8];   // 32 KB: [g][row 0..255][8m]

  const int tid = threadIdx.x;
  const int lane = tid & 63;
  const int wid = tid >> 6;        // 0..1 -> rows wid*128..+127
  const int l31 = lane & 31;
  const int khalf = lane >> 5;     // 0..1
  const int bid = blockIdx.x;
  const int xcd = bid & 7;
  const int cb = xcd >> 1;                      // col-quarter per XCD-pair
  const int rb = (xcd & 1) * 64 + (bid >> 3);   // 0..127 (256-row tiles)
  const char* Wb = (const char*)(Wcat + (size_t)cb * 260 * 4096);
  const int rbase = wid * 128 + l31;            // + rt*32, rt = 0..3

  char* const sBb = (char*)&sB[0][0];

  auto stageChunk = [&](int c, int slotIdx) {   // 8 KB, 4 loads/thread
    const char* src = Wb + (size_t)c * 8192;
    char* dst = sBb + slotIdx * 8192;
#pragma unroll
    for (int it = 0; it < 4; ++it) {
      int off = (it * 128 + tid) * 16;
      gload_lds16(src + off, dst + off);
    }
  };

  // prologue: a-tile (32 KB, 16 loads/thread) + chunks 0,1
  {
    const char* aSrc = (const char*)(a16s + (size_t)rb * 16384);
#pragma unroll
    for (int it = 0; it < 16; ++it) {
      int off = (it * 128 + tid) * 16;
      gload_lds16(aSrc + off, (char*)sAa + off);
    }
  }
  stageChunk(0, 0);
  stageChunk(1, 1);
  asm volatile("s_waitcnt vmcnt(0)" ::: "memory");
  __builtin_amdgcn_s_barrier();

  f32x16 acc[4][2];
#pragma unroll
  for (int rt = 0; rt < 4; ++rt)
#pragma unroll
    for (int ct = 0; ct < 2; ++ct)
#pragma unroll
      for (int r = 0; r < 16; ++r) acc[rt][ct][r] = 0.f;

  f16x8 xv[4][4];
  auto loadXV = [&](int er) {
#pragma unroll
    for (int rt = 0; rt < 4; ++rt)
#pragma unroll
      for (int ks = 0; ks < 4; ++ks) {
        const float* s = x + ((size_t)rb * 256 + rbase + rt * 32) * 256
                           + er * 64 + ks * 16 + khalf * 8;
        float4 u0 = *(const float4*)s;
        float4 u1 = *(const float4*)(s + 4);
        xv[rt][ks] = cvt8(u0, u1);
      }
  };

  // per-lane B offset within an 8 KB chunk: + ks*2048 + ct*512
  const int bOff = khalf * 1024 + l31 * 16;

  f16x8 as8[4];

  for (int q8g = 0; q8g < 32; ++q8g) {
    const int q8 = q8g * 8;
    if ((q8 & 63) == 0) loadXV(q8 >> 6);   // 32 vm loads; absorbed by next vmcnt(4)
    {
      int g = (q8 & 63) >> 3;
#pragma unroll
      for (int rt = 0; rt < 4; ++rt)
        as8[rt] = *(const f16x8*)((const char*)sAa + ((g * 256) + rbase + rt * 32) * 16);
    }
#pragma unroll
    for (int u = 0; u < 8; ++u) {
      const int q = q8 + u;
      asm volatile("s_waitcnt vmcnt(4)" ::: "memory");  // chunk q landed (own loads)
      __builtin_amdgcn_s_barrier();                      // ... both waves'
      __builtin_amdgcn_sched_barrier(0);
      stageChunk(q + 2, (u + 2) & 3);                    // slot's last reader: 2 barriers ago
      const char* slotB = sBb + (size_t)(u & 3) * 8192 + bOff;
      f16x8 bf[8];
#pragma unroll
      for (int ks = 0; ks < 4; ++ks)
#pragma unroll
        for (int ct = 0; ct < 2; ++ct)
          bf[ks * 2 + ct] = *(const f16x8*)(slotB + ks * 2048 + ct * 512);
      __builtin_amdgcn_s_setprio(1);
#pragma unroll
      for (int ks = 0; ks < 4; ++ks)
#pragma unroll
        for (int rt = 0; rt < 4; ++rt) {
          f16x8 af = xv[rt][ks] * as8[rt][u];
#pragma unroll
          for (int ct = 0; ct < 2; ++ct)
            acc[rt][ct] = __builtin_amdgcn_mfma_f32_32x32x16_f16(
                af, bf[ks * 2 + ct], acc[rt][ct], 0, 0, 0);
        }
      __builtin_amdgcn_s_setprio(0);
    }
  }

  // bias chunk (q=256, slot 0): outstanding = chunk 257's 4 loads after wait.
  asm volatile("s_waitcnt vmcnt(4)" ::: "memory");
  __builtin_amdgcn_s_barrier();
  {
    const char* slotB = sBb + 0 * 8192 + bOff;
#pragma unroll
    for (int ks = 0; ks < 4; ++ks) {
      int g = ks * 2 + khalf;
#pragma unroll
      for (int rt = 0; rt < 4; ++rt) {
        f16x8 af = *(const f16x8*)((const char*)sAa + ((g * 256) + rbase + rt * 32) * 16);
#pragma unroll
        for (int ct = 0; ct < 2; ++ct) {
          f16x8 bf = *(const f16x8*)(slotB + ks * 2048 + ct * 512);
          acc[rt][ct] = __builtin_amdgcn_mfma_f32_32x32x16_f16(af, bf, acc[rt][ct], 0, 0, 0);
        }
      }
    }
  }

  // store: row = rb*256 + rbase-part + rt*32 + (r&3)+8*(r>>2)+4*khalf;
  //        col = cb*64 + ct*32 + l31
#pragma unroll
  for (int rt = 0; rt < 4; ++rt)
#pragma unroll
    for (int ct = 0; ct < 2; ++ct)
#pragma unroll
      for (int r = 0; r < 16; ++r) {
        int rowin = (r & 3) + 8 * (r >> 2) + 4 * khalf;
        size_t row = (size_t)rb * 256 + wid * 128 + rt * 32 + rowin;
        int col = cb * 64 + ct * 32 + l31;
        sel[row * 256 + col] = (f16)acc[rt][ct][r];
      }
}

// ---------------------------------------------------------------------------
extern "C" void kernel_launch(void* const* d_in, const int* in_sizes, int n_in,
                              void* d_out, int out_size, void* d_ws, size_t ws_size,
                              hipStream_t stream) {
  (void)in_sizes; (void)n_in; (void)out_size;
  const float* x   = (const float*)d_in[0];
  const float* ctx = (const float*)d_in[1];
  const float* Wm  = (const float*)d_in[2];
  const float* bm  = (const float*)d_in[3];
  const float* cm  = (const float*)d_in[4];
  const float* um  = (const float*)d_in[5];
  const float* vm  = (const float*)d_in[6];
  const float* W1  = (const float*)d_in[7];
  const float* b1  = (const float*)d_in[8];
  const float* W2  = (const float*)d_in[9];
  const float* b2  = (const float*)d_in[10];
  const float* Wi  = (const float*)d_in[11];
  const float* bi  = (const float*)d_in[12];
  float* out = (float*)d_out;

  char* ws = (char*)d_ws;
  size_t off = 0;
  // Wcat: 4 col-quarters x 260 sub-chunk slots x 8KB
  f16* Wcat = (f16*)(ws + off); off += (size_t)4 * 260 * 4096 * 2;
  f16* W1t  = (f16*)(ws + off); off += (size_t)512 * 256 * 2;
  f16* W2t  = (f16*)(ws + off); off += (size_t)64 * 512 * 2;
  f16* umt  = (f16*)(ws + off); off += (size_t)64 * 256 * 2;
  f16* Wit  = (f16*)(ws + off); off += (size_t)256 * 512 * 2;
  f16* h16  = (f16*)(ws + off); off += (size_t)32768 * 512 * 2;
  float* logits = (float*)(ws + off); off += (size_t)32768 * 64 * 4;
  float* glog   = (float*)(ws + off); off += (size_t)32768 * 64 * 4;
  f16* a16s  = (f16*)(ws + off); off += (size_t)32768 * 64 * 2;
  f16* sel16 = (f16*)(ws + off); off += (size_t)32768 * 256 * 2;
  if (ws_size < off) return;

  // ---- weight prep ----
  prep_wcat_kernel<<<dim3(2056), dim3(256), 0, stream>>>(Wm, bm, cm, Wcat);
  prep_b_kernel<<<dim3(16384 / 256), dim3(256), 0, stream>>>(W1, W1t, 256, 256, 16384);
  prep_b_kernel<<<dim3(4096 / 256),  dim3(256), 0, stream>>>(W2, W2t, 512, 64, 4096);
  prep_b_kernel<<<dim3(2048 / 256),  dim3(256), 0, stream>>>(um, umt, 256, 64, 2048);
  prep_b_kernel<<<dim3(16384 / 256), dim3(256), 0, stream>>>(Wi, Wit, 512, 256, 16384);

  // ---- phase A: selector ----
  gemm_tpl<256, 4, 4, 1><<<dim3(256, 2), dim3(512), 0, stream>>>(
      ctx, 256, nullptr, 0, W1t, b1, nullptr, h16, 512);
  gemm_tpl<64, 4, 4, 0><<<dim3(256, 1), dim3(256), 0, stream>>>(
      x, 256, nullptr, 0, umt, nullptr, glog, nullptr, 64);
  gemm_tpl<64, 8, 0, 0><<<dim3(256, 1), dim3(256), 0, stream>>>(
      nullptr, 0, h16, 512, W2t, nullptr, logits, nullptr, 64);
  selector_finish<<<dim3(32768 / 4), dim3(256), 0, stream>>>(logits, glog, b2, vm, a16s);

  // ---- phase B: the 275-TFLOP contraction ----
  big_gemm<<<dim3(512), dim3(128), 0, stream>>>(x, a16s, Wcat, sel16);

  // ---- phase C: integrate([x, selected]) ----
  gemm_tpl<256, 8, 4, 0><<<dim3(256, 1), dim3(512), 0, stream>>>(
      x, 256, sel16, 256, Wit, bi, out, nullptr, 256);
}